// Round 6
// baseline (295.270 us; speedup 1.0000x reference)
//
#include <hip/hip_runtime.h>

typedef unsigned short US;
typedef __bf16 bf16x8 __attribute__((ext_vector_type(8)));
typedef float f32x4 __attribute__((ext_vector_type(4)));

__device__ __forceinline__ US f2bf(float f) {
  union { float f; unsigned u; } v; v.f = f;
  unsigned r = v.u + 0x7fffu + ((v.u >> 16) & 1u);
  return (US)(r >> 16);
}

// ---------------- kernel 0: pw_w fp32 -> bf16 ----------------
__global__ __launch_bounds__(256) void k_convw(const float* __restrict__ pw,
                                               US* __restrict__ wb) {
  int i = (blockIdx.x * 256 + threadIdx.x) * 4;
  float4 v = *(const float4*)(pw + i);
  ushort4 s;
  s.x = f2bf(v.x); s.y = f2bf(v.y); s.z = f2bf(v.z); s.w = f2bf(v.w);
  *(ushort4*)(wb + i) = s;
}

// ---------------- kernel 1: depthwise 7x7 -> y8 [b][c/8][px][8c] ----------------
// 512 blocks (16 b x 32 cg); 8 waves/block = 8 channels; wave covers the full
// 64x64 plane: 64 lanes = 16 col-strips x 4 row-bands of 16 rows. Vertical
// reuse via accumulator-parallelism: ONE live L[12] row, acc[16][4], all
// array indices compile-time (SROA-clean, same pattern as the R4 kernel).
__global__ __launch_bounds__(512, 4) void k_dw(const float* __restrict__ x,
                                               const float* __restrict__ dww,
                                               const float* __restrict__ dwb,
                                               US* __restrict__ y8) {
  const int bid = blockIdx.x;           // 16b * 32cg
  const int cg  = bid & 31;
  const int b   = bid >> 5;
  const int t   = threadIdx.x;
  const int w   = t >> 6;               // wave id = channel slot 0..7
  const int l   = t & 63;
  const int s   = l & 15;               // col strip (4 cols)
  const int band = l >> 4;              // row band (16 rows)
  const int c   = __builtin_amdgcn_readfirstlane(cg * 8 + w);  // wave-uniform
  const float* xp = x + ((size_t)b * 256 + c) * 4096;
  float wv[49];
  const float* wp = dww + c * 49;       // scalar base -> s_load -> SGPRs
#pragma unroll
  for (int i = 0; i < 49; ++i) wv[i] = wp[i];
  const float bias = dwb[c];

  const int bcx   = s * 4;              // output col base
  const int rbase = band * 16;          // output row base

  __shared__ US t8[8][4096];

  float acc[16][4];
#pragma unroll
  for (int o = 0; o < 16; ++o)
#pragma unroll
    for (int q = 0; q < 4; ++q) acc[o][q] = bias;

  const float4 fz = {0.f, 0.f, 0.f, 0.f};
#pragma unroll
  for (int j = 0; j < 22; ++j) {
    const int r = rbase - 3 + j;        // input row
    float L[12];                        // cols bcx-4 .. bcx+7 (single live row)
    if ((unsigned)r < 64u) {
      const float* rp = xp + r * 64 + bcx;
      float4 a_ = (bcx >= 4) ? *(const float4*)(rp - 4) : fz;
      float4 b_ = *(const float4*)(rp);
      float4 c_ = (bcx < 60) ? *(const float4*)(rp + 4) : fz;
      L[0]=a_.x; L[1]=a_.y; L[2]=a_.z;  L[3]=a_.w;
      L[4]=b_.x; L[5]=b_.y; L[6]=b_.z;  L[7]=b_.w;
      L[8]=c_.x; L[9]=c_.y; L[10]=c_.z; L[11]=c_.w;
    } else {
#pragma unroll
      for (int z = 0; z < 12; ++z) L[z] = 0.f;
    }
#pragma unroll
    for (int o = 0; o < 16; ++o) {
      if (j - o >= 0 && j - o <= 6) {   // compile-time after unroll
        const int kh = j - o;
#pragma unroll
        for (int kw = 0; kw < 7; ++kw) {
          const float wk = wv[kh * 7 + kw];
#pragma unroll
          for (int q = 0; q < 4; ++q)
            acc[o][q] = fmaf(L[q + kw + 1], wk, acc[o][q]);
        }
      }
    }
  }

  // write this thread's 16 output rows to the channel-major LDS tile
#pragma unroll
  for (int o = 0; o < 16; ++o) {
    ushort4 sv;
    sv.x = f2bf(acc[o][0]); sv.y = f2bf(acc[o][1]);
    sv.z = f2bf(acc[o][2]); sv.w = f2bf(acc[o][3]);
    *(ushort4*)&t8[w][(rbase + o) * 64 + bcx] = sv;
  }
  __syncthreads();

  // pack epilogue: y8[b][cg][px][8c]; lane t covers px pairs -> 32B contiguous
  const size_t ybase = ((size_t)b * 32 + cg) * 4096;
#pragma unroll
  for (int it = 0; it < 4; ++it) {
    const int px = it * 1024 + t * 2;
    unsigned rc[8];
#pragma unroll
    for (int c2 = 0; c2 < 8; ++c2) rc[c2] = *(const unsigned*)&t8[c2][px];
    uint4 A, B2;
    A.x  = __builtin_amdgcn_perm(rc[1], rc[0], 0x05040100u);  // even px: c0..c7
    A.y  = __builtin_amdgcn_perm(rc[3], rc[2], 0x05040100u);
    A.z  = __builtin_amdgcn_perm(rc[5], rc[4], 0x05040100u);
    A.w  = __builtin_amdgcn_perm(rc[7], rc[6], 0x05040100u);
    B2.x = __builtin_amdgcn_perm(rc[1], rc[0], 0x07060302u);  // odd px
    B2.y = __builtin_amdgcn_perm(rc[3], rc[2], 0x07060302u);
    B2.z = __builtin_amdgcn_perm(rc[5], rc[4], 0x07060302u);
    B2.w = __builtin_amdgcn_perm(rc[7], rc[6], 0x07060302u);
    US* yb = y8 + (ybase + px) * 8;
    *(uint4*)(yb)     = A;
    *(uint4*)(yb + 8) = B2;
  }
}

// ---------------- kernel 2: pointwise GEMM (MFMA bf16) ----------------
// out^T fragments via swapped operands; double-buffered LDS; XCD swizzle.
// per batch: out[512][4096] = W(512x256) x Y^T ; tile 128o x 128px, BK=64
__global__ __launch_bounds__(256, 2) void k_pw(const US* __restrict__ y8,
                                               const US* __restrict__ wb,
                                               const float* __restrict__ pwb,
                                               float* __restrict__ out) {
  // bijective XCD swizzle (nwg=2048, %8==0): chunk of 256 per XCD
  const int bid = blockIdx.x;
  const int s   = ((bid & 7) << 8) | (bid >> 3);
  const int b   = s >> 7;
  const int rr  = s & 127;
  const int nt  = rr >> 2;        // px tile (32)
  const int mt  = rr & 3;         // o tile (4) innermost -> y8-tile L2 reuse
  const int o0  = mt * 128;
  const int hw0 = nt * 128;

  __shared__ US lsA[2][128][72];
  __shared__ US lsB[2][128][72];
  const int tid  = threadIdx.x;
  const int lane = tid & 63;
  const int wid  = tid >> 6;
  const int wm   = wid >> 1, wn = wid & 1;
  const int strow = tid >> 3;     // A-stage: 0..31
  const int scg   = tid & 7;      // A-stage: 16B chunk within 128B k-row
  const int bg    = tid >> 5;     // B-stage: 8c-group 0..7
  const int bl    = tid & 31;     // B-stage: px within group of 32

  const f32x4 fzero = {0.f, 0.f, 0.f, 0.f};
  f32x4 acc[4][4];
#pragma unroll
  for (int m = 0; m < 4; ++m)
#pragma unroll
    for (int n = 0; n < 4; ++n) acc[m][n] = fzero;

  uint4 ra[4], rb[4];
  // prologue: stage kt=0 into buffer 0
#pragma unroll
  for (int i = 0; i < 4; ++i) {
    ra[i] = *(const uint4*)(wb + (size_t)(o0 + i * 32 + strow) * 256 + scg * 8);
    rb[i] = *(const uint4*)(y8 + ((size_t)(b * 32 + bg) * 4096 + hw0 + bl + 32 * i) * 8);
  }
#pragma unroll
  for (int i = 0; i < 4; ++i) {
    *(uint4*)&lsA[0][i * 32 + strow][scg * 8] = ra[i];
    *(uint4*)&lsB[0][bl + 32 * i][bg * 8]     = rb[i];
  }
  __syncthreads();

  for (int kt = 0; kt < 4; ++kt) {
    const int cur = kt & 1;
    // issue-early: global loads for next tile (hide under compute)
    if (kt < 3) {
      const int ck = (kt + 1) * 64;
#pragma unroll
      for (int i = 0; i < 4; ++i) {
        ra[i] = *(const uint4*)(wb + (size_t)(o0 + i * 32 + strow) * 256 + ck + scg * 8);
        rb[i] = *(const uint4*)(y8 + ((size_t)(b * 32 + (ck >> 3) + bg) * 4096 + hw0 + bl + 32 * i) * 8);
      }
    }
    bf16x8 af[2][4], bfr[2][4];
#pragma unroll
    for (int kk = 0; kk < 2; ++kk) {
      const int kcol = kk * 32 + (lane >> 4) * 8;
#pragma unroll
      for (int m = 0; m < 4; ++m)
        af[kk][m] = *reinterpret_cast<const bf16x8*>(&lsA[cur][wm * 64 + m * 16 + (lane & 15)][kcol]);
#pragma unroll
      for (int n = 0; n < 4; ++n)
        bfr[kk][n] = *reinterpret_cast<const bf16x8*>(&lsB[cur][wn * 64 + n * 16 + (lane & 15)][kcol]);
    }
#pragma unroll
    for (int kk = 0; kk < 2; ++kk)
#pragma unroll
      for (int m = 0; m < 4; ++m)
#pragma unroll
        for (int n = 0; n < 4; ++n)
          // swapped operands: acc = (Y^T)*(W^T) = out^T fragment
          acc[m][n] = __builtin_amdgcn_mfma_f32_16x16x32_bf16(bfr[kk][n], af[kk][m], acc[m][n], 0, 0, 0);

    if (kt < 3) {
#pragma unroll
      for (int i = 0; i < 4; ++i) {
        *(uint4*)&lsA[cur ^ 1][i * 32 + strow][scg * 8] = ra[i];
        *(uint4*)&lsB[cur ^ 1][bl + 32 * i][bg * 8]     = rb[i];
      }
      __syncthreads();
    }
  }

  // epilogue: D^T layout -> lane holds 4 consecutive px at fixed o: dwordx4 stores
#pragma unroll
  for (int m = 0; m < 4; ++m) {
    const int o  = o0 + wm * 64 + m * 16 + (lane & 15);
    const float bv = pwb[o];
    float* orow = out + (((size_t)b * 512 + o) * 4096) + hw0 + wn * 64 + (lane >> 4) * 4;
#pragma unroll
    for (int n = 0; n < 4; ++n) {
      f32x4 v = acc[m][n];
      v[0] += bv; v[1] += bv; v[2] += bv; v[3] += bv;
      __builtin_nontemporal_store(v, (f32x4*)(orow + n * 16));
    }
  }
}

extern "C" void kernel_launch(void* const* d_in, const int* in_sizes, int n_in,
                              void* d_out, int out_size, void* d_ws, size_t ws_size,
                              hipStream_t stream) {
  const float* x   = (const float*)d_in[0];
  const float* dww = (const float*)d_in[1];
  const float* dwb = (const float*)d_in[2];
  const float* pww = (const float*)d_in[3];
  const float* pwb = (const float*)d_in[4];
  float* out = (float*)d_out;

  char* ws = (char*)d_ws;
  US* y8  = (US*)ws;                         // 16*32*4096*8 bf16 = 33,554,432 B
  US* wbf = (US*)(ws + 33554432);            // 512*256 bf16 = 262,144 B

  k_convw<<<128, 256, 0, stream>>>(pww, wbf);
  k_dw   <<<512, 512, 0, stream>>>(x, dww, dwb, y8);
  k_pw   <<<2048, 256, 0, stream>>>(y8, wbf, pwb, out);
}

// Round 7
// 138.156 us; speedup vs baseline: 2.1372x; 2.1372x over previous
//
#include <hip/hip_runtime.h>

typedef unsigned short US;
typedef __bf16 bf16x8 __attribute__((ext_vector_type(8)));
typedef float f32x4 __attribute__((ext_vector_type(4)));

__device__ __forceinline__ US f2bf(float f) {
  union { float f; unsigned u; } v; v.f = f;
  unsigned r = v.u + 0x7fffu + ((v.u >> 16) & 1u);
  return (US)(r >> 16);
}

// ---------------- kernel 0: pw_w fp32 -> bf16 ----------------
__global__ __launch_bounds__(256) void k_convw(const float* __restrict__ pw,
                                               US* __restrict__ wb) {
  int i = (blockIdx.x * 256 + threadIdx.x) * 4;
  float4 v = *(const float4*)(pw + i);
  ushort4 s;
  s.x = f2bf(v.x); s.y = f2bf(v.y); s.z = f2bf(v.z); s.w = f2bf(v.w);
  *(ushort4*)(wb + i) = s;
}

// ---------------- kernel 1: depthwise 7x7 -> y8 [b][c/8][px][8c] ----------------
// 512 blocks (16 b x 32 cg); 8 waves/block = 8 channels; wave covers the full
// 64x64 plane: 64 lanes = 16 col-strips x 4 row-bands of 16 rows. Vertical
// reuse via 16 NAMED f32x4 accumulators + fully-literal macro-unrolled steps:
// no runtime-indexed arrays anywhere -> cannot spill via SROA failure.
__global__ __launch_bounds__(512, 2) void k_dw(const float* __restrict__ x,
                                               const float* __restrict__ dww,
                                               const float* __restrict__ dwb,
                                               US* __restrict__ y8) {
  const int bid = blockIdx.x;           // 16b * 32cg
  const int cg  = bid & 31;
  const int b   = bid >> 5;
  const int t   = threadIdx.x;
  const int w   = t >> 6;               // wave id = channel slot 0..7
  const int l   = t & 63;
  const int s   = l & 15;               // col strip (4 cols)
  const int band = l >> 4;              // row band (16 rows)
  const int c   = __builtin_amdgcn_readfirstlane(cg * 8 + w);  // wave-uniform
  const float* xp = x + ((size_t)b * 256 + c) * 4096;
  float wv[49];
  const float* wp = dww + c * 49;       // scalar base -> s_load -> SGPRs
#pragma unroll
  for (int i = 0; i < 49; ++i) wv[i] = wp[i];
  const float bias = dwb[c];

  const int bcx   = s * 4;              // output col base
  const int rbase = band * 16;          // output row base

  __shared__ US t8[8][4096];
  const float4 fz = {0.f, 0.f, 0.f, 0.f};

#define ACC_(O) vacc##O
  f32x4 vacc0, vacc1, vacc2, vacc3, vacc4, vacc5, vacc6, vacc7,
        vacc8, vacc9, vacc10, vacc11, vacc12, vacc13, vacc14, vacc15;
#define INITACC(O) ACC_(O)[0] = bias; ACC_(O)[1] = bias; ACC_(O)[2] = bias; ACC_(O)[3] = bias;
  INITACC(0) INITACC(1) INITACC(2) INITACC(3) INITACC(4) INITACC(5) INITACC(6) INITACC(7)
  INITACC(8) INITACC(9) INITACC(10) INITACC(11) INITACC(12) INITACC(13) INITACC(14) INITACC(15)

#define DOROW(J, O)                                                          \
  if constexpr ((J) >= (O) && (J) - (O) <= 6) {                              \
    constexpr int kh_ = (J) - (O);                                           \
    _Pragma("unroll")                                                        \
    for (int kw = 0; kw < 7; ++kw) {                                         \
      const float wk = wv[kh_ * 7 + kw];                                     \
      ACC_(O)[0] = fmaf(L[kw + 1], wk, ACC_(O)[0]);                          \
      ACC_(O)[1] = fmaf(L[kw + 2], wk, ACC_(O)[1]);                          \
      ACC_(O)[2] = fmaf(L[kw + 3], wk, ACC_(O)[2]);                          \
      ACC_(O)[3] = fmaf(L[kw + 4], wk, ACC_(O)[3]);                          \
    }                                                                        \
  }

#define STEP(J)                                                              \
  {                                                                          \
    const int r_ = rbase - 3 + (J);                                          \
    float L[12];                                                             \
    if ((unsigned)r_ < 64u) {                                                \
      const float* rp = xp + r_ * 64 + bcx;                                  \
      float4 a_ = (bcx >= 4) ? *(const float4*)(rp - 4) : fz;                \
      float4 b_ = *(const float4*)(rp);                                      \
      float4 c_ = (bcx < 60) ? *(const float4*)(rp + 4) : fz;                \
      L[0] = a_.x; L[1] = a_.y; L[2]  = a_.z; L[3]  = a_.w;                  \
      L[4] = b_.x; L[5] = b_.y; L[6]  = b_.z; L[7]  = b_.w;                  \
      L[8] = c_.x; L[9] = c_.y; L[10] = c_.z; L[11] = c_.w;                  \
    } else {                                                                 \
      L[0]=0.f;L[1]=0.f;L[2]=0.f;L[3]=0.f;L[4]=0.f;L[5]=0.f;                 \
      L[6]=0.f;L[7]=0.f;L[8]=0.f;L[9]=0.f;L[10]=0.f;L[11]=0.f;               \
    }                                                                        \
    DOROW(J, 0)  DOROW(J, 1)  DOROW(J, 2)  DOROW(J, 3)                       \
    DOROW(J, 4)  DOROW(J, 5)  DOROW(J, 6)  DOROW(J, 7)                       \
    DOROW(J, 8)  DOROW(J, 9)  DOROW(J, 10) DOROW(J, 11)                      \
    DOROW(J, 12) DOROW(J, 13) DOROW(J, 14) DOROW(J, 15)                      \
  }

  STEP(0)  STEP(1)  STEP(2)  STEP(3)  STEP(4)  STEP(5)  STEP(6)  STEP(7)
  STEP(8)  STEP(9)  STEP(10) STEP(11) STEP(12) STEP(13) STEP(14) STEP(15)
  STEP(16) STEP(17) STEP(18) STEP(19) STEP(20) STEP(21)

  // write this thread's 16 output rows to the channel-major LDS tile
#define STOREROW(O)                                                          \
  {                                                                          \
    ushort4 sv;                                                              \
    sv.x = f2bf(ACC_(O)[0]); sv.y = f2bf(ACC_(O)[1]);                        \
    sv.z = f2bf(ACC_(O)[2]); sv.w = f2bf(ACC_(O)[3]);                        \
    *(ushort4*)&t8[w][(rbase + (O)) * 64 + bcx] = sv;                        \
  }
  STOREROW(0)  STOREROW(1)  STOREROW(2)  STOREROW(3)
  STOREROW(4)  STOREROW(5)  STOREROW(6)  STOREROW(7)
  STOREROW(8)  STOREROW(9)  STOREROW(10) STOREROW(11)
  STOREROW(12) STOREROW(13) STOREROW(14) STOREROW(15)
  __syncthreads();

  // pack epilogue: y8[b][cg][px][8c]; lane t covers px pairs -> 32B contiguous
  const size_t ybase = ((size_t)b * 32 + cg) * 4096;
#pragma unroll
  for (int it = 0; it < 4; ++it) {
    const int px = it * 1024 + t * 2;
    unsigned rc[8];
#pragma unroll
    for (int c2 = 0; c2 < 8; ++c2) rc[c2] = *(const unsigned*)&t8[c2][px];
    uint4 A, B2;
    A.x  = __builtin_amdgcn_perm(rc[1], rc[0], 0x05040100u);  // even px: c0..c7
    A.y  = __builtin_amdgcn_perm(rc[3], rc[2], 0x05040100u);
    A.z  = __builtin_amdgcn_perm(rc[5], rc[4], 0x05040100u);
    A.w  = __builtin_amdgcn_perm(rc[7], rc[6], 0x05040100u);
    B2.x = __builtin_amdgcn_perm(rc[1], rc[0], 0x07060302u);  // odd px
    B2.y = __builtin_amdgcn_perm(rc[3], rc[2], 0x07060302u);
    B2.z = __builtin_amdgcn_perm(rc[5], rc[4], 0x07060302u);
    B2.w = __builtin_amdgcn_perm(rc[7], rc[6], 0x07060302u);
    US* yb = y8 + (ybase + px) * 8;
    *(uint4*)(yb)     = A;
    *(uint4*)(yb + 8) = B2;
  }
#undef ACC_
#undef INITACC
#undef DOROW
#undef STEP
#undef STOREROW
}

// ---------------- kernel 2: pointwise GEMM (MFMA bf16) ----------------
// out^T fragments via swapped operands; double-buffered LDS; XCD swizzle.
// per batch: out[512][4096] = W(512x256) x Y^T ; tile 128o x 128px, BK=64
__global__ __launch_bounds__(256, 2) void k_pw(const US* __restrict__ y8,
                                               const US* __restrict__ wb,
                                               const float* __restrict__ pwb,
                                               float* __restrict__ out) {
  // bijective XCD swizzle (nwg=2048, %8==0): chunk of 256 per XCD
  const int bid = blockIdx.x;
  const int s   = ((bid & 7) << 8) | (bid >> 3);
  const int b   = s >> 7;
  const int rr  = s & 127;
  const int nt  = rr >> 2;        // px tile (32)
  const int mt  = rr & 3;         // o tile (4) innermost -> y8-tile L2 reuse
  const int o0  = mt * 128;
  const int hw0 = nt * 128;

  __shared__ US lsA[2][128][72];
  __shared__ US lsB[2][128][72];
  const int tid  = threadIdx.x;
  const int lane = tid & 63;
  const int wid  = tid >> 6;
  const int wm   = wid >> 1, wn = wid & 1;
  const int strow = tid >> 3;     // A-stage: 0..31
  const int scg   = tid & 7;      // A-stage: 16B chunk within 128B k-row
  const int bg    = tid >> 5;     // B-stage: 8c-group 0..7
  const int bl    = tid & 31;     // B-stage: px within group of 32

  const f32x4 fzero = {0.f, 0.f, 0.f, 0.f};
  f32x4 acc[4][4];
#pragma unroll
  for (int m = 0; m < 4; ++m)
#pragma unroll
    for (int n = 0; n < 4; ++n) acc[m][n] = fzero;

  uint4 ra[4], rb[4];
  // prologue: stage kt=0 into buffer 0
#pragma unroll
  for (int i = 0; i < 4; ++i) {
    ra[i] = *(const uint4*)(wb + (size_t)(o0 + i * 32 + strow) * 256 + scg * 8);
    rb[i] = *(const uint4*)(y8 + ((size_t)(b * 32 + bg) * 4096 + hw0 + bl + 32 * i) * 8);
  }
#pragma unroll
  for (int i = 0; i < 4; ++i) {
    *(uint4*)&lsA[0][i * 32 + strow][scg * 8] = ra[i];
    *(uint4*)&lsB[0][bl + 32 * i][bg * 8]     = rb[i];
  }
  __syncthreads();

  for (int kt = 0; kt < 4; ++kt) {
    const int cur = kt & 1;
    // issue-early: global loads for next tile (hide under compute)
    if (kt < 3) {
      const int ck = (kt + 1) * 64;
#pragma unroll
      for (int i = 0; i < 4; ++i) {
        ra[i] = *(const uint4*)(wb + (size_t)(o0 + i * 32 + strow) * 256 + ck + scg * 8);
        rb[i] = *(const uint4*)(y8 + ((size_t)(b * 32 + (ck >> 3) + bg) * 4096 + hw0 + bl + 32 * i) * 8);
      }
    }
    bf16x8 af[2][4], bfr[2][4];
#pragma unroll
    for (int kk = 0; kk < 2; ++kk) {
      const int kcol = kk * 32 + (lane >> 4) * 8;
#pragma unroll
      for (int m = 0; m < 4; ++m)
        af[kk][m] = *reinterpret_cast<const bf16x8*>(&lsA[cur][wm * 64 + m * 16 + (lane & 15)][kcol]);
#pragma unroll
      for (int n = 0; n < 4; ++n)
        bfr[kk][n] = *reinterpret_cast<const bf16x8*>(&lsB[cur][wn * 64 + n * 16 + (lane & 15)][kcol]);
    }
#pragma unroll
    for (int kk = 0; kk < 2; ++kk)
#pragma unroll
      for (int m = 0; m < 4; ++m)
#pragma unroll
        for (int n = 0; n < 4; ++n)
          // swapped operands: acc = (Y^T)*(W^T) = out^T fragment
          acc[m][n] = __builtin_amdgcn_mfma_f32_16x16x32_bf16(bfr[kk][n], af[kk][m], acc[m][n], 0, 0, 0);

    if (kt < 3) {
#pragma unroll
      for (int i = 0; i < 4; ++i) {
        *(uint4*)&lsA[cur ^ 1][i * 32 + strow][scg * 8] = ra[i];
        *(uint4*)&lsB[cur ^ 1][bl + 32 * i][bg * 8]     = rb[i];
      }
      __syncthreads();
    }
  }

  // epilogue: D^T layout -> lane holds 4 consecutive px at fixed o: dwordx4 stores
#pragma unroll
  for (int m = 0; m < 4; ++m) {
    const int o  = o0 + wm * 64 + m * 16 + (lane & 15);
    const float bv = pwb[o];
    float* orow = out + (((size_t)b * 512 + o) * 4096) + hw0 + wn * 64 + (lane >> 4) * 4;
#pragma unroll
    for (int n = 0; n < 4; ++n) {
      f32x4 v = acc[m][n];
      v[0] += bv; v[1] += bv; v[2] += bv; v[3] += bv;
      __builtin_nontemporal_store(v, (f32x4*)(orow + n * 16));
    }
  }
}

extern "C" void kernel_launch(void* const* d_in, const int* in_sizes, int n_in,
                              void* d_out, int out_size, void* d_ws, size_t ws_size,
                              hipStream_t stream) {
  const float* x   = (const float*)d_in[0];
  const float* dww = (const float*)d_in[1];
  const float* dwb = (const float*)d_in[2];
  const float* pww = (const float*)d_in[3];
  const float* pwb = (const float*)d_in[4];
  float* out = (float*)d_out;

  char* ws = (char*)d_ws;
  US* y8  = (US*)ws;                         // 16*32*4096*8 bf16 = 33,554,432 B
  US* wbf = (US*)(ws + 33554432);            // 512*256 bf16 = 262,144 B

  k_convw<<<128, 256, 0, stream>>>(pww, wbf);
  k_dw   <<<512, 512, 0, stream>>>(x, dww, dwb, y8);
  k_pw   <<<2048, 256, 0, stream>>>(y8, wbf, pwb, out);
}

// Round 8
// 91.663 us; speedup vs baseline: 3.2212x; 1.5072x over previous
//
#include <hip/hip_runtime.h>

typedef unsigned short US;
typedef __bf16 bf16x8 __attribute__((ext_vector_type(8)));
typedef float f32x4 __attribute__((ext_vector_type(4)));

__device__ __forceinline__ US f2bf(float f) {
  union { float f; unsigned u; } v; v.f = f;
  unsigned r = v.u + 0x7fffu + ((v.u >> 16) & 1u);
  return (US)(r >> 16);
}

// ---------------- kernel 0: pw_w fp32 -> bf16 ----------------
__global__ __launch_bounds__(256) void k_convw(const float* __restrict__ pw,
                                               US* __restrict__ wb) {
  int i = (blockIdx.x * 256 + threadIdx.x) * 4;
  float4 v = *(const float4*)(pw + i);
  ushort4 s;
  s.x = f2bf(v.x); s.y = f2bf(v.y); s.z = f2bf(v.z); s.w = f2bf(v.w);
  *(ushort4*)(wb + i) = s;
}

// ---------------- kernel 1: depthwise 7x7 -> y8 [b][c/8][px][8c] ----------------
// R4 shape (proven): 2048 blocks (b x cg x rg), 8 waves = 8 channels, thread =
// 4 rows x 4 cols. NEW: branch-free loads — clamped row address, cndmask'd
// column offset, select-to-zero — so all 30 loads/thread are unconditional
// and the scheduler can hoist/pipeline them (R4 was latency-bound on guarded
// load->use chains).
__global__ __launch_bounds__(512) void k_dw(const float* __restrict__ x,
                                            const float* __restrict__ dww,
                                            const float* __restrict__ dwb,
                                            US* __restrict__ y8) {
  const int bid = blockIdx.x;           // b(16) * cg(32) * rg(4)
  const int rg  = bid & 3;
  const int cg  = (bid >> 2) & 31;
  const int b   = bid >> 7;
  const int t   = threadIdx.x;
  const int w   = t >> 6;               // wave id = channel slot 0..7
  const int l   = t & 63;
  const int g   = l >> 4;               // row quad 0..3
  const int cb  = l & 15;               // col quad 0..15
  const int c   = __builtin_amdgcn_readfirstlane(cg * 8 + w);  // wave-uniform
  const float* xp = x + ((size_t)b * 256 + c) * 4096;
  float wv[49];
  const float* wp = dww + c * 49;       // scalar base -> s_load -> SGPRs
#pragma unroll
  for (int i = 0; i < 49; ++i) wv[i] = wp[i];
  const float bias = dwb[c];

  const int r0  = rg * 16;
  const int br  = r0 + g * 4;           // output row base
  const int bcx = cb * 4;               // output col base

  const bool colL = (bcx >= 4);         // left quad in-image?
  const bool colR = (bcx < 60);         // right quad in-image?
  const int offL  = colL ? -4 : 0;      // cndmask'd offsets, no branch
  const int offR  = colR ?  4 : 0;

  float acc[4][4];
#pragma unroll
  for (int o = 0; o < 4; ++o)
#pragma unroll
    for (int q = 0; q < 4; ++q) acc[o][q] = bias;

#pragma unroll
  for (int j = 0; j < 10; ++j) {
    const int r   = br - 3 + j;          // input row
    const int rc  = min(max(r, 0), 63);  // clamped address, always valid
    const bool rowOK = ((unsigned)r < 64u);
    const float* rp = xp + rc * 64 + bcx;
    float4 a_ = *(const float4*)(rp + offL);   // unconditional loads
    float4 b_ = *(const float4*)(rp);
    float4 c_ = *(const float4*)(rp + offR);
    const bool okL = rowOK && colL;
    const bool okR = rowOK && colR;
    float L[12];
    L[0] = okL   ? a_.x : 0.f; L[1]  = okL   ? a_.y : 0.f;
    L[2] = okL   ? a_.z : 0.f; L[3]  = okL   ? a_.w : 0.f;
    L[4] = rowOK ? b_.x : 0.f; L[5]  = rowOK ? b_.y : 0.f;
    L[6] = rowOK ? b_.z : 0.f; L[7]  = rowOK ? b_.w : 0.f;
    L[8] = okR   ? c_.x : 0.f; L[9]  = okR   ? c_.y : 0.f;
    L[10]= okR   ? c_.z : 0.f; L[11] = okR   ? c_.w : 0.f;
#pragma unroll
    for (int o = 0; o < 4; ++o) {
      if (j - o >= 0 && j - o <= 6) {    // compile-time after unroll
        const int kh = j - o;
#pragma unroll
        for (int kw = 0; kw < 7; ++kw) {
          const float wk = wv[kh * 7 + kw];
#pragma unroll
          for (int q = 0; q < 4; ++q)
            acc[o][q] = fmaf(L[q + kw + 1], wk, acc[o][q]);
        }
      }
    }
  }

  // LDS transpose: [8c][1024 px], then pack px-pairs into y8 uint4s
  __shared__ US t8[8][1024];
#pragma unroll
  for (int o = 0; o < 4; ++o) {
    ushort4 s;
    s.x = f2bf(acc[o][0]); s.y = f2bf(acc[o][1]);
    s.z = f2bf(acc[o][2]); s.w = f2bf(acc[o][3]);
    *(ushort4*)&t8[w][(g * 4 + o) * 64 + bcx] = s;
  }
  __syncthreads();

  unsigned rc8[8];
#pragma unroll
  for (int c2 = 0; c2 < 8; ++c2) rc8[c2] = *(const unsigned*)&t8[c2][2 * t];
  uint4 A, B2;
  A.x  = __builtin_amdgcn_perm(rc8[1], rc8[0], 0x05040100u);  // px even: c0..c7
  A.y  = __builtin_amdgcn_perm(rc8[3], rc8[2], 0x05040100u);
  A.z  = __builtin_amdgcn_perm(rc8[5], rc8[4], 0x05040100u);
  A.w  = __builtin_amdgcn_perm(rc8[7], rc8[6], 0x05040100u);
  B2.x = __builtin_amdgcn_perm(rc8[1], rc8[0], 0x07060302u);  // px odd
  B2.y = __builtin_amdgcn_perm(rc8[3], rc8[2], 0x07060302u);
  B2.z = __builtin_amdgcn_perm(rc8[5], rc8[4], 0x07060302u);
  B2.w = __builtin_amdgcn_perm(rc8[7], rc8[6], 0x07060302u);
  US* yb = y8 + (((size_t)b * 32 + cg) * 4096 + r0 * 64) * 8 + (size_t)t * 16;
  *(uint4*)(yb)     = A;
  *(uint4*)(yb + 8) = B2;
}

// ---------------- kernel 2: pointwise GEMM (MFMA bf16) ----------------
// out^T fragments via swapped operands; double-buffered LDS; XCD swizzle.
// per batch: out[512][4096] = W(512x256) x Y^T ; tile 128o x 128px, BK=64
__global__ __launch_bounds__(256, 2) void k_pw(const US* __restrict__ y8,
                                               const US* __restrict__ wb,
                                               const float* __restrict__ pwb,
                                               float* __restrict__ out) {
  // bijective XCD swizzle (nwg=2048, %8==0): chunk of 256 per XCD
  const int bid = blockIdx.x;
  const int s   = ((bid & 7) << 8) | (bid >> 3);
  const int b   = s >> 7;
  const int rr  = s & 127;
  const int nt  = rr >> 2;        // px tile (32)
  const int mt  = rr & 3;         // o tile (4) innermost -> y8-tile L2 reuse
  const int o0  = mt * 128;
  const int hw0 = nt * 128;

  __shared__ US lsA[2][128][72];
  __shared__ US lsB[2][128][72];
  const int tid  = threadIdx.x;
  const int lane = tid & 63;
  const int wid  = tid >> 6;
  const int wm   = wid >> 1, wn = wid & 1;
  const int strow = tid >> 3;     // A-stage: 0..31
  const int scg   = tid & 7;      // A-stage: 16B chunk within 128B k-row
  const int bg    = tid >> 5;     // B-stage: 8c-group 0..7
  const int bl    = tid & 31;     // B-stage: px within group of 32

  const f32x4 fzero = {0.f, 0.f, 0.f, 0.f};
  f32x4 acc[4][4];
#pragma unroll
  for (int m = 0; m < 4; ++m)
#pragma unroll
    for (int n = 0; n < 4; ++n) acc[m][n] = fzero;

  uint4 ra[4], rb[4];
  // prologue: stage kt=0 into buffer 0
#pragma unroll
  for (int i = 0; i < 4; ++i) {
    ra[i] = *(const uint4*)(wb + (size_t)(o0 + i * 32 + strow) * 256 + scg * 8);
    rb[i] = *(const uint4*)(y8 + ((size_t)(b * 32 + bg) * 4096 + hw0 + bl + 32 * i) * 8);
  }
#pragma unroll
  for (int i = 0; i < 4; ++i) {
    *(uint4*)&lsA[0][i * 32 + strow][scg * 8] = ra[i];
    *(uint4*)&lsB[0][bl + 32 * i][bg * 8]     = rb[i];
  }
  __syncthreads();

  for (int kt = 0; kt < 4; ++kt) {
    const int cur = kt & 1;
    // issue-early: global loads for next tile (hide under compute)
    if (kt < 3) {
      const int ck = (kt + 1) * 64;
#pragma unroll
      for (int i = 0; i < 4; ++i) {
        ra[i] = *(const uint4*)(wb + (size_t)(o0 + i * 32 + strow) * 256 + ck + scg * 8);
        rb[i] = *(const uint4*)(y8 + ((size_t)(b * 32 + (ck >> 3) + bg) * 4096 + hw0 + bl + 32 * i) * 8);
      }
    }
    bf16x8 af[2][4], bfr[2][4];
#pragma unroll
    for (int kk = 0; kk < 2; ++kk) {
      const int kcol = kk * 32 + (lane >> 4) * 8;
#pragma unroll
      for (int m = 0; m < 4; ++m)
        af[kk][m] = *reinterpret_cast<const bf16x8*>(&lsA[cur][wm * 64 + m * 16 + (lane & 15)][kcol]);
#pragma unroll
      for (int n = 0; n < 4; ++n)
        bfr[kk][n] = *reinterpret_cast<const bf16x8*>(&lsB[cur][wn * 64 + n * 16 + (lane & 15)][kcol]);
    }
#pragma unroll
    for (int kk = 0; kk < 2; ++kk)
#pragma unroll
      for (int m = 0; m < 4; ++m)
#pragma unroll
        for (int n = 0; n < 4; ++n)
          // swapped operands: acc = (Y^T)*(W^T) = out^T fragment
          acc[m][n] = __builtin_amdgcn_mfma_f32_16x16x32_bf16(bfr[kk][n], af[kk][m], acc[m][n], 0, 0, 0);

    if (kt < 3) {
#pragma unroll
      for (int i = 0; i < 4; ++i) {
        *(uint4*)&lsA[cur ^ 1][i * 32 + strow][scg * 8] = ra[i];
        *(uint4*)&lsB[cur ^ 1][bl + 32 * i][bg * 8]     = rb[i];
      }
      __syncthreads();
    }
  }

  // epilogue: D^T layout -> lane holds 4 consecutive px at fixed o: dwordx4 stores
#pragma unroll
  for (int m = 0; m < 4; ++m) {
    const int o  = o0 + wm * 64 + m * 16 + (lane & 15);
    const float bv = pwb[o];
    float* orow = out + (((size_t)b * 512 + o) * 4096) + hw0 + wn * 64 + (lane >> 4) * 4;
#pragma unroll
    for (int n = 0; n < 4; ++n) {
      f32x4 v = acc[m][n];
      v[0] += bv; v[1] += bv; v[2] += bv; v[3] += bv;
      __builtin_nontemporal_store(v, (f32x4*)(orow + n * 16));
    }
  }
}

extern "C" void kernel_launch(void* const* d_in, const int* in_sizes, int n_in,
                              void* d_out, int out_size, void* d_ws, size_t ws_size,
                              hipStream_t stream) {
  const float* x   = (const float*)d_in[0];
  const float* dww = (const float*)d_in[1];
  const float* dwb = (const float*)d_in[2];
  const float* pww = (const float*)d_in[3];
  const float* pwb = (const float*)d_in[4];
  float* out = (float*)d_out;

  char* ws = (char*)d_ws;
  US* y8  = (US*)ws;                         // 16*32*4096*8 bf16 = 33,554,432 B
  US* wbf = (US*)(ws + 33554432);            // 512*256 bf16 = 262,144 B

  k_convw<<<128,  256, 0, stream>>>(pww, wbf);
  k_dw   <<<2048, 512, 0, stream>>>(x, dww, dwb, y8);
  k_pw   <<<2048, 256, 0, stream>>>(y8, wbf, pwb, out);
}